// Round 7
// baseline (2073.182 us; speedup 1.0000x reference)
//
#include <hip/hip_runtime.h>

// HighOrderActivationA: per (b,g): sort 4 inputs asc with argsort indices,
// coef = [s0, s1-s0, s2-s1, s3-s2], idx[k] = suffix-sum of (1<<ind[j]) for j>=k,
// out[b,g,:] = sum_k coef[k] * params[g, idx[k], :]   (O=16)
//
// B=8192, G=256, arity=4, O=16, fp32.  160MB unique traffic -> ~27us roofline.
// Kernel ~72us (dur 157.7 = ~85us harness poison-fill + kernel).
//
// R7 theory: vmcnt store-ack serialization.  Throughput models (VALU ~6us,
// LDS ~10us, HBM ~25us) leave ~45us unexplained, and the kernel has been
// insensitive to staging bytes (R1), block lifetime (R3), DRAM ordering
// (R5: -10us), nt hints (R6: -3.5us).  Latency model: 16 waves/SIMD x
// ~10,800cyc serial makespan = 72us.  The in-loop stores share the in-order
// vmcnt queue with the prefetched X loads, so each row's s_waitcnt before
// consuming xs[r] transitively waits on prior STORE completion acks
// (~600-900cyc L2 write-commit each) -- ~7k cyc/wave of hidden serialization.
//
// R7 change (single variable vs R6): DEFER ALL STORES out of the compute
// loop.  Results overwrite xs[r] in place (flat ~32-reg pressure, no spill
// under the 128-VGPR cap), stores issued as one batch at the end.  During
// compute the vmcnt queue holds only loads; stores drain at wave exit.
//
// Structure otherwise unchanged from R6: g-tile fast grid, 64-row strip,
// stage 16 tables once + 1 barrier, 8 consecutive rows/wave, plain (non-nt)
// 1KB-contiguous wave stores.

typedef float f32x4 __attribute__((ext_vector_type(4)));

#define NT 512         // threads per block (8 waves)
#define TG 16          // groups per block
#define ROWS 64        // b-rows per block (8 per wave)
#define RPW 8          // consecutive rows per wave
#define TSTRIDE 260    // 16 rows * 16 floats + 4 pad

__global__ __launch_bounds__(NT, 4) void hoa_kernel(
    const float* __restrict__ X, const float* __restrict__ P,
    float* __restrict__ out, int B, int G)
{
    __shared__ float lds[TG * TSTRIDE];   // 16.25 KB

    const int tid = threadIdx.x;
    const int g0 = blockIdx.x * TG;       // g-tile: FAST block dim (locality)
    const int b0 = blockIdx.y * ROWS;     // b-strip: slow block dim

    // ---- stage TG param tables (1024 float4, 2 per thread), once ----
#pragma unroll
    for (int i = 0; i < 2; ++i) {
        int idx = tid + i * NT;               // 0..1023
        int table = idx >> 6;                 // 0..15
        int within = idx & 63;                // float4 index within table
        f32x4 v = *reinterpret_cast<const f32x4*>(
            P + (size_t)(g0 + table) * 256 + within * 4);
        *reinterpret_cast<f32x4*>(&lds[table * TSTRIDE + within * 4]) = v;
    }
    __syncthreads();

    const int c  = tid & 3;          // output float4 chunk
    const int gg = (tid >> 2) & 15;  // group within tile
    const int wv = tid >> 6;         // wave id 0..7
    const int g  = g0 + gg;
    const int brow = b0 + wv * RPW;  // first of 8 consecutive rows

    const float* tab = &lds[gg * TSTRIDE + c * 4];
    const float* xp  = X   + (size_t)brow * (G * 4)  + g * 4;
    float*       op  = out + (size_t)brow * (G * 16) + g * 16 + c * 4;
    const size_t xstride = (size_t)G * 4;    // 1 row in X (floats)
    const size_t ostride = (size_t)G * 16;   // 1 row in out (floats)

    // ---- issue all 8 row-loads up front: HBM latency overlap ----
    f32x4 xs[RPW];
#pragma unroll
    for (int r = 0; r < RPW; ++r) {
        if (brow + r < B)
            xs[r] = *reinterpret_cast<const f32x4*>(xp + r * xstride);
    }

    // ---- compute all rows into registers; NO stores in this loop so the
    //      vmcnt queue contains only loads (no store-ack serialization) ----
#pragma unroll
    for (int r = 0; r < RPW; ++r) {
        if (brow + r >= B) continue;
        float v0 = xs[r].x, v1 = xs[r].y, v2 = xs[r].z, v3 = xs[r].w;
        int i0 = 0, i1 = 1, i2 = 2, i3 = 3;

        // ---- branchless 4-element sorting network with index tracking ----
#define CSWAP(va, vb, ia, ib)                         \
        {                                             \
            bool sw_ = (va) > (vb);                   \
            float lo_ = sw_ ? (vb) : (va);            \
            float hi_ = sw_ ? (va) : (vb);            \
            int il_ = sw_ ? (ib) : (ia);              \
            int ih_ = sw_ ? (ia) : (ib);              \
            (va) = lo_; (vb) = hi_; (ia) = il_; (ib) = ih_; \
        }
        CSWAP(v0, v1, i0, i1);
        CSWAP(v2, v3, i2, i3);
        CSWAP(v0, v2, i0, i2);
        CSWAP(v1, v3, i1, i3);
        CSWAP(v1, v2, i1, i2);
#undef CSWAP

        // ---- coefficients & suffix-sum bit indices ----
        float c0 = v0, c1 = v1 - v0, c2 = v2 - v1, c3 = v3 - v2;
        int idx0 = 15;
        int idx1 = 15 ^ (1 << i0);
        int idx2 = idx1 ^ (1 << i1);
        int idx3 = 1 << i3;

        // ---- gather this chunk (float4) of 4 table rows from LDS ----
        f32x4 A  = *reinterpret_cast<const f32x4*>(tab + idx0 * 16);
        f32x4 Bv = *reinterpret_cast<const f32x4*>(tab + idx1 * 16);
        f32x4 C  = *reinterpret_cast<const f32x4*>(tab + idx2 * 16);
        f32x4 D  = *reinterpret_cast<const f32x4*>(tab + idx3 * 16);

        f32x4 o;
        o.x = fmaf(c3, D.x, fmaf(c2, C.x, fmaf(c1, Bv.x, c0 * A.x)));
        o.y = fmaf(c3, D.y, fmaf(c2, C.y, fmaf(c1, Bv.y, c0 * A.y)));
        o.z = fmaf(c3, D.z, fmaf(c2, C.z, fmaf(c1, Bv.z, c0 * A.z)));
        o.w = fmaf(c3, D.w, fmaf(c2, C.w, fmaf(c1, Bv.w, c0 * A.w)));

        xs[r] = o;   // overwrite input slot: flat register pressure
    }

    // ---- batched store storm: 8 x 1KB contiguous wave stores, issued
    //      back-to-back, drain at wave exit (overlapped across waves) ----
#pragma unroll
    for (int r = 0; r < RPW; ++r) {
        if (brow + r < B)
            *reinterpret_cast<f32x4*>(op + r * ostride) = xs[r];
    }
}

extern "C" void kernel_launch(void* const* d_in, const int* in_sizes, int n_in,
                              void* d_out, int out_size, void* d_ws, size_t ws_size,
                              hipStream_t stream) {
    const float* X = (const float*)d_in[0];
    const float* P = (const float*)d_in[1];
    float* out = (float*)d_out;

    // params: [G, 16, 16] -> G = size/256 ; X: [B, G*4] -> B = size/(G*4)
    int G = in_sizes[1] / 256;
    int B = in_sizes[0] / (G * 4);

    dim3 grid(G / TG, (B + ROWS - 1) / ROWS);   // x = g-tile (fast), y = b-strip
    hipLaunchKernelGGL(hoa_kernel, grid, dim3(NT), 0, stream, X, P, out, B, G);
}

// Round 8
// 192.953 us; speedup vs baseline: 10.7445x; 10.7445x over previous
//
#include <hip/hip_runtime.h>

// HighOrderActivationA: per (b,g): sort 4 inputs asc with argsort indices,
// coef = [s0, s1-s0, s2-s1, s3-s2], idx[k] = suffix-sum of (1<<ind[j]) for j>=k,
// out[b,g,:] = sum_k coef[k] * params[g, idx[k], :]   (O=16)
//
// B=8192, G=256, arity=4, O=16, fp32.  160MB unique traffic -> ~27us roofline.
// R6 kernel = 74us (calibrated via R7: harness dur = kernel + exactly one
// 83us poison-fill).
//
// R8: DROP LDS ENTIRELY -- gather params straight from L2.
//   Evidence: R7's scratch blowup (WRITE_SIZE 6.8GB, VGPR 56) confirmed the
//   counters pipeline works and killed the vmcnt theory (FIFO count: stores
//   issued after load L_r never delay L_r's wait).  Remaining suspects for
//   74us vs 27us: the LDS apparatus. Bank math for the gather,
//   bank = (4*(gg+c) + 16*(idx&1)) % 32, gives data-dependent 2-4-way
//   conflicts (~1.6x on the LDS floor), plus staging + barrier + block-shape
//   constraints.  params = 256KB total = fully L2-resident (4MB/XCD, ~34.5
//   TB/s) -- staging it in LDS is Common-mistake #7.
//
// New shape: one block = one b-row.  1024 threads = 256 groups x 4 chunks.
//   - X:   4KB contiguous read per block (16B per (b,g), shared by 4 lanes).
//   - out: 16KB contiguous write per block -- near-sequential global stream.
//   - gathers: 4 x 16B per thread from P at data-dependent row idx; ~537MB
//     of L2 line traffic (~16us @ 34.5TB/s), concurrent with HBM streams.
//   - No LDS, no barrier, no loops; ~35 VGPR -> 32 waves/CU for latency hiding.
// Plain (non-nt) accesses per R6 A/B.  No arrays, no conditionals -> no
// scratch (R7 lesson).

typedef float f32x4 __attribute__((ext_vector_type(4)));

#define NT 1024

__global__ __launch_bounds__(NT, 8) void hoa_kernel(
    const float* __restrict__ X, const float* __restrict__ P,
    float* __restrict__ out, int B, int G)
{
    const int b = blockIdx.x;           // one block per b-row
    const int n = G * 4;                // thread-slots per row (1024 for G=256)

    const float* xrow = X   + (size_t)b * n;
    float*       orow = out + (size_t)b * (G * 16);

    for (int i = threadIdx.x; i < n; i += NT) {
        const int c = i & 3;            // output float4 chunk
        const int g = i >> 2;           // group

        // ---- 16B input for this (b,g); 4 sibling lanes share the line ----
        f32x4 x = *reinterpret_cast<const f32x4*>(xrow + g * 4);
        float v0 = x.x, v1 = x.y, v2 = x.z, v3 = x.w;
        int i0 = 0, i1 = 1, i2 = 2, i3 = 3;

        // ---- branchless 4-element sorting network with index tracking ----
#define CSWAP(va, vb, ia, ib)                         \
        {                                             \
            bool sw_ = (va) > (vb);                   \
            float lo_ = sw_ ? (vb) : (va);            \
            float hi_ = sw_ ? (va) : (vb);            \
            int il_ = sw_ ? (ib) : (ia);              \
            int ih_ = sw_ ? (ia) : (ib);              \
            (va) = lo_; (vb) = hi_; (ia) = il_; (ib) = ih_; \
        }
        CSWAP(v0, v1, i0, i1);
        CSWAP(v2, v3, i2, i3);
        CSWAP(v0, v2, i0, i2);
        CSWAP(v1, v3, i1, i3);
        CSWAP(v1, v2, i1, i2);
#undef CSWAP

        // ---- coefficients & suffix-sum bit indices ----
        float c0 = v0, c1 = v1 - v0, c2 = v2 - v1, c3 = v3 - v2;
        int idx0 = 15;
        int idx1 = 15 ^ (1 << i0);
        int idx2 = idx1 ^ (1 << i1);
        int idx3 = 1 << i3;

        // ---- gather 4 table rows' chunk straight from L2-resident P ----
        const float* tp = P + (size_t)g * 256 + c * 4;
        f32x4 A  = *reinterpret_cast<const f32x4*>(tp + idx0 * 16);
        f32x4 Bv = *reinterpret_cast<const f32x4*>(tp + idx1 * 16);
        f32x4 C  = *reinterpret_cast<const f32x4*>(tp + idx2 * 16);
        f32x4 D  = *reinterpret_cast<const f32x4*>(tp + idx3 * 16);

        f32x4 o;
        o.x = fmaf(c3, D.x, fmaf(c2, C.x, fmaf(c1, Bv.x, c0 * A.x)));
        o.y = fmaf(c3, D.y, fmaf(c2, C.y, fmaf(c1, Bv.y, c0 * A.y)));
        o.z = fmaf(c3, D.z, fmaf(c2, C.z, fmaf(c1, Bv.z, c0 * A.z)));
        o.w = fmaf(c3, D.w, fmaf(c2, C.w, fmaf(c1, Bv.w, c0 * A.w)));

        // ---- store: block writes one contiguous 16KB output row ----
        *reinterpret_cast<f32x4*>(orow + i * 4) = o;
    }
}

extern "C" void kernel_launch(void* const* d_in, const int* in_sizes, int n_in,
                              void* d_out, int out_size, void* d_ws, size_t ws_size,
                              hipStream_t stream) {
    const float* X = (const float*)d_in[0];
    const float* P = (const float*)d_in[1];
    float* out = (float*)d_out;

    // params: [G, 16, 16] -> G = size/256 ; X: [B, G*4] -> B = size/(G*4)
    int G = in_sizes[1] / 256;
    int B = in_sizes[0] / (G * 4);

    hipLaunchKernelGGL(hoa_kernel, dim3(B), dim3(NT), 0, stream, X, P, out, B, G);
}

// Round 9
// 176.047 us; speedup vs baseline: 11.7763x; 1.0960x over previous
//
#include <hip/hip_runtime.h>

// HighOrderActivationA: per (b,g): sort 4 inputs asc with argsort indices,
// coef = [s0, s1-s0, s2-s1, s3-s2], idx[k] = suffix-sum of (1<<ind[j]) for j>=k,
// out[b,g,:] = sum_k coef[k] * params[g, idx[k], :]   (O=16)
//
// B=8192, G=256, arity=4, O=16, fp32.  160MB unique traffic -> ~27us roofline.
// Calibration: harness dur = kernel + one 83us poison-fill.  R6 kernel = 74us.
//
// Ledger: staging bytes (R1 null), block lifetime (R3 null), DRAM ordering
// (R5 -10us), nt (R6 -3.5us), store-defer via array (R7: scratch blowup,
// rule #20), L2-gather instead of LDS (R8: +36us, LDS exonerated; R7 counter
// shows LDS conflicts <= ~6us).
//
// R9 theory: WRITE RUN LENGTH.  The harness fill hits 84% of peak at 9.5%
// occupancy -> streaming BW needs no occupancy, it needs long contiguous
// runs (fill: ~256KB/block).  R6 waves wrote 1KB runs at 16KB stride across
// a 1MB span x ~1024 co-resident blocks = DRAM page thrash; R5's -10us was
// a weak version of this fix.
//
// R9 structure: wave = ONE ROW x 64 groups -> the wave's 4 stores fully
// paint a 4KB contiguous run.  Thread = one (b,g): sort computed once (was
// 4x), X loads fully distinct 16B/lane.  TG=64 tables staged once (66.5KB
// LDS, XOR-swizzled: slot ^ ((table>>3)&7), bijective per table, spreads
// the mod-8 bank classes of the new gather mapping).  1024 thr = 16 waves,
// 4 barrier-free row-iterations, X prefetched into NAMED registers (no
// dynamically indexed arrays -- R7 lesson).  512 blocks = 2/CU.

typedef float f32x4 __attribute__((ext_vector_type(4)));

#define NT 1024        // threads per block (16 waves)
#define TG 64          // groups (tables) per block
#define ROWS 64        // b-rows per block
#define WPB 16         // waves per block = rows per iteration
#define TSTRIDE 260    // floats per table slab (64 f32x4 + 4 pad, 16B aligned)

__device__ __forceinline__ void row_compute_store(
    f32x4 x, const float* tab, int key, float* obase)
{
    float v0 = x.x, v1 = x.y, v2 = x.z, v3 = x.w;
    int i0 = 0, i1 = 1, i2 = 2, i3 = 3;

    // ---- branchless 4-element sorting network with index tracking ----
#define CSWAP(va, vb, ia, ib)                         \
    {                                                 \
        bool sw_ = (va) > (vb);                       \
        float lo_ = sw_ ? (vb) : (va);                \
        float hi_ = sw_ ? (va) : (vb);                \
        int il_ = sw_ ? (ib) : (ia);                  \
        int ih_ = sw_ ? (ia) : (ib);                  \
        (va) = lo_; (vb) = hi_; (ia) = il_; (ib) = ih_; \
    }
    CSWAP(v0, v1, i0, i1);
    CSWAP(v2, v3, i2, i3);
    CSWAP(v0, v2, i0, i2);
    CSWAP(v1, v3, i1, i3);
    CSWAP(v1, v2, i1, i2);
#undef CSWAP

    // ---- coefficients & suffix-sum bit indices ----
    float c0 = v0, c1 = v1 - v0, c2 = v2 - v1, c3 = v3 - v2;
    int idx0 = 15;
    int idx1 = 15 ^ (1 << i0);
    int idx2 = idx1 ^ (1 << i1);
    int idx3 = 1 << i3;

    // ---- gather 4 table rows (4 x 16 floats) from swizzled LDS, fma,
    //      store 4 consecutive f32x4 (wave paints 4KB contiguous) ----
#pragma unroll
    for (int k = 0; k < 4; ++k) {
        f32x4 A  = *reinterpret_cast<const f32x4*>(tab + 4 * ((idx0 * 4 + k) ^ key));
        f32x4 Bv = *reinterpret_cast<const f32x4*>(tab + 4 * ((idx1 * 4 + k) ^ key));
        f32x4 C  = *reinterpret_cast<const f32x4*>(tab + 4 * ((idx2 * 4 + k) ^ key));
        f32x4 D  = *reinterpret_cast<const f32x4*>(tab + 4 * ((idx3 * 4 + k) ^ key));
        f32x4 o;
        o.x = fmaf(c3, D.x, fmaf(c2, C.x, fmaf(c1, Bv.x, c0 * A.x)));
        o.y = fmaf(c3, D.y, fmaf(c2, C.y, fmaf(c1, Bv.y, c0 * A.y)));
        o.z = fmaf(c3, D.z, fmaf(c2, C.z, fmaf(c1, Bv.z, c0 * A.z)));
        o.w = fmaf(c3, D.w, fmaf(c2, C.w, fmaf(c1, Bv.w, c0 * A.w)));
        *reinterpret_cast<f32x4*>(obase + k * 4) = o;
    }
}

__global__ __launch_bounds__(NT, 4) void hoa_kernel(
    const float* __restrict__ X, const float* __restrict__ P,
    float* __restrict__ out, int B, int G)
{
    __shared__ float lds[TG * TSTRIDE];   // 66.56 KB

    const int tid = threadIdx.x;
    const int g0 = blockIdx.x * TG;       // g-tile (fast dim for locality)
    const int b0 = blockIdx.y * ROWS;

    // ---- stage TG tables once, XOR-swizzled: slot w -> w ^ ((t>>3)&7) ----
#pragma unroll
    for (int i = 0; i < (TG * 64) / NT; ++i) {   // 4 f32x4 per thread
        int idx = tid + i * NT;
        int t = idx >> 6;                 // table 0..63
        int w = idx & 63;                 // f32x4 slot within table
        f32x4 v = *reinterpret_cast<const f32x4*>(
            P + (size_t)(g0 + t) * 256 + w * 4);
        int ws = w ^ ((t >> 3) & 7);      // bijective within table
        *reinterpret_cast<f32x4*>(&lds[t * TSTRIDE + ws * 4]) = v;
    }
    __syncthreads();

    const int gg = tid & 63;              // group within tile == lane
    const int wv = tid >> 6;              // wave id 0..15 == row within iter
    const int g  = g0 + gg;
    const float* tab = &lds[gg * TSTRIDE];
    const int key = (gg >> 3) & 7;        // must match staging swizzle

    const int r0 = b0 + wv;
    const int r1 = r0 + WPB, r2 = r1 + WPB, r3 = r2 + WPB;

    // ---- prefetch all 4 row-inputs into NAMED registers (no arrays) ----
    // X row: wave reads 64 x 16B = 1KB contiguous.
    f32x4 x0, x1, x2, x3;
    if (r0 < B) x0 = *reinterpret_cast<const f32x4*>(X + (size_t)r0 * (G * 4) + g * 4);
    if (r1 < B) x1 = *reinterpret_cast<const f32x4*>(X + (size_t)r1 * (G * 4) + g * 4);
    if (r2 < B) x2 = *reinterpret_cast<const f32x4*>(X + (size_t)r2 * (G * 4) + g * 4);
    if (r3 < B) x3 = *reinterpret_cast<const f32x4*>(X + (size_t)r3 * (G * 4) + g * 4);

    // ---- 4 row-iterations, no barriers; guards are wave-uniform ----
    if (r0 < B) row_compute_store(x0, tab, key, out + (size_t)r0 * (G * 16) + (size_t)g * 16);
    if (r1 < B) row_compute_store(x1, tab, key, out + (size_t)r1 * (G * 16) + (size_t)g * 16);
    if (r2 < B) row_compute_store(x2, tab, key, out + (size_t)r2 * (G * 16) + (size_t)g * 16);
    if (r3 < B) row_compute_store(x3, tab, key, out + (size_t)r3 * (G * 16) + (size_t)g * 16);
}

extern "C" void kernel_launch(void* const* d_in, const int* in_sizes, int n_in,
                              void* d_out, int out_size, void* d_ws, size_t ws_size,
                              hipStream_t stream) {
    const float* X = (const float*)d_in[0];
    const float* P = (const float*)d_in[1];
    float* out = (float*)d_out;

    // params: [G, 16, 16] -> G = size/256 ; X: [B, G*4] -> B = size/(G*4)
    int G = in_sizes[1] / 256;
    int B = in_sizes[0] / (G * 4);

    dim3 grid(G / TG, (B + ROWS - 1) / ROWS);   // (4, 128) for 8192x256
    hipLaunchKernelGGL(hoa_kernel, grid, dim3(NT), 0, stream, X, P, out, B, G);
}

// Round 11
// 166.670 us; speedup vs baseline: 12.4388x; 1.0563x over previous
//
#include <hip/hip_runtime.h>

// HighOrderActivationA: per (b,g): sort 4 inputs asc with argsort indices,
// coef = [s0, s1-s0, s2-s1, s3-s2], idx[k] = suffix-sum of (1<<ind[j]) for j>=k,
// out[b,g,:] = sum_k coef[k] * params[g, idx[k], :]   (O=16)
//
// B=8192, G=256, arity=4, O=16, fp32.  160MB unique -> ~27us roofline.
// Calibration: harness dur = kernel + one ~83us poison-fill.  Best: R6 = 74us.
//
// R11 = R10 resubmitted unchanged (R10 bench was an infra failure: container
// failed twice; no compile error, no counters -> no evidence to act on).
//
// Ledger: R1 staging-bytes null; R3 block-lifetime null; R5 grid-order -10;
// R6 no-nt -3.5; R7 scratch blowup (rule #20; also proved DRAM does 4TB/s
// under chaos -> R6's 2.16TB/s is NOT a DRAM ceiling); R8 L2-gather +36
// (LDS exonerated); R9 sort-once +19 (64B-stride scattered stores killed it
// -> per-instruction store DENSITY matters).
//
// R10: single-variable vs R6 -- WAVE-LEVEL STORE RUN LENGTH.  R6's wave
// wrote 1KB runs at 16KB stride; the 6.7TB/s fill writes long ascending
// runs per wave.  R10 keeps R6's thread role (c,gg16), sort, LDS layout,
// bank math, and dense 1KB wave-stores IDENTICAL; only iteration order
// changes: TG=64 tables/block, wave = one row x 64 groups via q=0..3
// quarters -> 4 consecutive 1KB stores form a 4KB ascending contiguous run
// (and X loads a 1KB ascending run).  512 blocks = exactly 2/CU (66.5KB
// LDS; static >64KB works on this toolchain, proven R9), 32 waves/CU same
// as R6, no residency tail.  All named regs, wave-uniform guards.

typedef float f32x4 __attribute__((ext_vector_type(4)));

#define NT 1024        // threads per block (16 waves)
#define TG 64          // groups (tables) per block
#define RPW 4          // rows per wave
#define ROWS (16 * RPW) // 64 b-rows per block
#define TSTRIDE 260    // 16 rows * 16 floats + 4 pad per table

__device__ __forceinline__ f32x4 one_chunk(f32x4 x, const float* tab)
{
    float v0 = x.x, v1 = x.y, v2 = x.z, v3 = x.w;
    int i0 = 0, i1 = 1, i2 = 2, i3 = 3;

    // ---- branchless 4-element sorting network with index tracking ----
#define CSWAP(va, vb, ia, ib)                         \
    {                                                 \
        bool sw_ = (va) > (vb);                       \
        float lo_ = sw_ ? (vb) : (va);                \
        float hi_ = sw_ ? (va) : (vb);                \
        int il_ = sw_ ? (ib) : (ia);                  \
        int ih_ = sw_ ? (ia) : (ib);                  \
        (va) = lo_; (vb) = hi_; (ia) = il_; (ib) = ih_; \
    }
    CSWAP(v0, v1, i0, i1);
    CSWAP(v2, v3, i2, i3);
    CSWAP(v0, v2, i0, i2);
    CSWAP(v1, v3, i1, i3);
    CSWAP(v1, v2, i1, i2);
#undef CSWAP

    float c0 = v0, c1 = v1 - v0, c2 = v2 - v1, c3 = v3 - v2;
    int idx0 = 15;
    int idx1 = 15 ^ (1 << i0);
    int idx2 = idx1 ^ (1 << i1);
    int idx3 = 1 << i3;

    f32x4 A  = *reinterpret_cast<const f32x4*>(tab + idx0 * 16);
    f32x4 Bv = *reinterpret_cast<const f32x4*>(tab + idx1 * 16);
    f32x4 C  = *reinterpret_cast<const f32x4*>(tab + idx2 * 16);
    f32x4 D  = *reinterpret_cast<const f32x4*>(tab + idx3 * 16);

    f32x4 o;
    o.x = fmaf(c3, D.x, fmaf(c2, C.x, fmaf(c1, Bv.x, c0 * A.x)));
    o.y = fmaf(c3, D.y, fmaf(c2, C.y, fmaf(c1, Bv.y, c0 * A.y)));
    o.z = fmaf(c3, D.z, fmaf(c2, C.z, fmaf(c1, Bv.z, c0 * A.z)));
    o.w = fmaf(c3, D.w, fmaf(c2, C.w, fmaf(c1, Bv.w, c0 * A.w)));
    return o;
}

__global__ __launch_bounds__(NT, 2) void hoa_kernel(
    const float* __restrict__ X, const float* __restrict__ P,
    float* __restrict__ out, int B, int G)
{
    __shared__ float lds[TG * TSTRIDE];   // 66.56 KB -> 2 blocks/CU

    const int tid = threadIdx.x;
    const int g0 = blockIdx.x * TG;       // g-tile (fast dim)
    const int b0 = blockIdx.y * ROWS;

    // ---- stage TG tables once (linear layout, same bank math as R6) ----
#pragma unroll
    for (int i = 0; i < (TG * 64) / NT; ++i) {   // 4 f32x4 per thread
        int idx = tid + i * NT;
        int t = idx >> 6;                 // table 0..63
        int w = idx & 63;                 // f32x4 slot within table
        f32x4 v = *reinterpret_cast<const f32x4*>(
            P + (size_t)(g0 + t) * 256 + w * 4);
        *reinterpret_cast<f32x4*>(&lds[t * TSTRIDE + w * 4]) = v;
    }
    __syncthreads();

    const int c    = tid & 3;            // output float4 chunk
    const int gg16 = (tid >> 2) & 15;    // group within quarter
    const int wv   = tid >> 6;           // wave id 0..15

    // per-q LDS table base (q*16+gg16 is the table within the block tile)
    const float* tabq0 = &lds[(0 * 16 + gg16) * TSTRIDE + c * 4];
    const float* tabq1 = &lds[(1 * 16 + gg16) * TSTRIDE + c * 4];
    const float* tabq2 = &lds[(2 * 16 + gg16) * TSTRIDE + c * 4];
    const float* tabq3 = &lds[(3 * 16 + gg16) * TSTRIDE + c * 4];

#pragma unroll
    for (int rr = 0; rr < RPW; ++rr) {
        const int r = b0 + wv * RPW + rr;      // wave-uniform row
        if (r >= B) break;                     // uniform guard

        const float* xrow = X   + (size_t)r * (G * 4)  + g0 * 4;
        float*       orow = out + (size_t)r * (G * 16) + (size_t)g0 * 16;

        // ---- X: 4 loads, wave reads 1KB ascending contiguous ----
        f32x4 xq0 = *reinterpret_cast<const f32x4*>(xrow + (0 * 16 + gg16) * 4);
        f32x4 xq1 = *reinterpret_cast<const f32x4*>(xrow + (1 * 16 + gg16) * 4);
        f32x4 xq2 = *reinterpret_cast<const f32x4*>(xrow + (2 * 16 + gg16) * 4);
        f32x4 xq3 = *reinterpret_cast<const f32x4*>(xrow + (3 * 16 + gg16) * 4);

        // ---- 4 quarters: each store = dense 1KB wave-write, q ascending
        //      -> the wave paints a 4KB contiguous ascending run ----
        f32x4 o0 = one_chunk(xq0, tabq0);
        *reinterpret_cast<f32x4*>(orow + ((0 * 16 + gg16) * 16) + c * 4) = o0;
        f32x4 o1 = one_chunk(xq1, tabq1);
        *reinterpret_cast<f32x4*>(orow + ((1 * 16 + gg16) * 16) + c * 4) = o1;
        f32x4 o2 = one_chunk(xq2, tabq2);
        *reinterpret_cast<f32x4*>(orow + ((2 * 16 + gg16) * 16) + c * 4) = o2;
        f32x4 o3 = one_chunk(xq3, tabq3);
        *reinterpret_cast<f32x4*>(orow + ((3 * 16 + gg16) * 16) + c * 4) = o3;
    }
}

extern "C" void kernel_launch(void* const* d_in, const int* in_sizes, int n_in,
                              void* d_out, int out_size, void* d_ws, size_t ws_size,
                              hipStream_t stream) {
    const float* X = (const float*)d_in[0];
    const float* P = (const float*)d_in[1];
    float* out = (float*)d_out;

    // params: [G, 16, 16] -> G = size/256 ; X: [B, G*4] -> B = size/(G*4)
    int G = in_sizes[1] / 256;
    int B = in_sizes[0] / (G * 4);

    dim3 grid(G / TG, (B + ROWS - 1) / ROWS);   // (4, 128) = 512 blocks
    hipLaunchKernelGGL(hoa_kernel, grid, dim3(NT), 0, stream, X, P, out, B, G);
}